// Round 11
// baseline (121.378 us; speedup 1.0000x reference)
//
#include <hip/hip_runtime.h>
#include <hip/hip_bf16.h>

typedef float f32x4 __attribute__((ext_vector_type(4)));
typedef short bf16x8 __attribute__((ext_vector_type(8)));

#define ZT 16              // samples per workgroup
#define TL_COLS 160        // ring: 160 cols x 128 u ushorts = 40960 B
#define TL_RING (TL_COLS * 128)
#define YL_BUF 640         // 16 z * max padded span (5k * 8i)

// PATHS enumerated l1-major, l2, lo with |l1-l2|<=lo<=l1+l2
constexpr int cL1[15]  = {0,0,0,1,1,1,1,1,1,2,2,2,2,2,2};
constexpr int cL2[15]  = {0,1,2,0,1,1,1,2,2,0,1,1,2,2,2};
constexpr int cLO[15]  = {0,1,2,1,0,1,2,1,2,2,1,2,0,1,2};
constexpr int cCSZ[15] = {1,9,25,9,9,27,45,45,75,25,45,75,25,75,125};
constexpr int cCOFF[15]= {0,1,10,35,44,53,80,125,170,245,270,315,390,415,490}; // total 615
constexpr int cO1[3] = {0,128,512};  // x1 / out irrep block offsets (floats)
constexpr int cO2[3] = {0,1,4};      // x2 irrep block offsets

// Path sequence grouped by OUTPUT lo (acc peak 40 regs, per-lo epilogue),
// sub-grouped by l1 (x1c reloaded at 9 group starts, prefetched pre-barrier).
// Ring region: S even->0, S odd->80 cols; size 16*dO <= 80, consecutive disjoint.
constexpr int cSEQ[15] = {0,4,12, 1,3,5,7,10,13, 2,6,8,9,11,14};

struct CP { const float* p[15]; };

__device__ __forceinline__ ushort f2bf(float f) {
    union { __hip_bfloat16 h; ushort u; } c;
    c.h = __float2bfloat16(f);
    return c.u;
}

// ---- prep kernel: Wb[p][w][u] = bf16(ws[p][u][0][w]) (transpose + convert) ----
__global__ void prep_w(const float* __restrict__ ws, ushort* __restrict__ wb) {
    __shared__ float lds[64 * 132];
    const int p = blockIdx.x;
    const int tid = threadIdx.x;
    const float* src = ws + (size_t)p * 16384;
    ushort* dst = wb + (size_t)p * 16384;
    for (int half = 0; half < 2; ++half) {
        for (int i = tid; i < 8192; i += 256) {          // load 64 u-rows, coalesced
            int u = i >> 7, w = i & 127;
            lds[u * 132 + w] = src[(half * 64 + u) * 128 + w];
        }
        __syncthreads();
        for (int i = tid; i < 8192; i += 256) {          // store transposed, coalesced
            int w = i >> 6, u = i & 63;
            dst[w * 128 + half * 64 + u] = f2bf(lds[u * 132 + w]);
        }
        __syncthreads();
    }
}

// ---- y in K-MAJOR layout: ybuf[z*span_pad + k*ipad + i] = sum_j c[i,j,k]*x2[z,j] ----
template<int P>
__device__ __forceinline__ void compute_y(int tid, const float* __restrict__ cl,
                                          const float* __restrict__ x2l,
                                          float* __restrict__ ybuf) {
    constexpr int l2 = cL2[P], lo = cLO[P];
    constexpr int d1 = 2*cL1[P]+1, d2 = 2*l2+1, dO = 2*lo+1;
    constexpr int ipad = (d1 == 5) ? 8 : 4;
    constexpr int span_pad = dO * ipad;
    constexpr int ny = ZT * span_pad;
    for (int idx = tid; idx < ny; idx += 256) {
        const int z = idx / span_pad, rem = idx - z * span_pad;
        const int k = rem / ipad, i = rem & (ipad - 1);
        float s = 0.f;
        if (i < d1) {
            #pragma unroll
            for (int j = 0; j < d2; ++j)
                s += cl[cCOFF[P] + (i*d2 + j)*dO + k] * x2l[z*9 + cO2[l2] + j];
        }
        ybuf[idx] = s;   // pad slots get 0; never consumed
    }
}

// ---- load current l1-block of x1 into regs (thread: u-pair 2*lane, z=4*wv+r) ----
template<int L1>
__device__ __forceinline__ void load_x1(const float* __restrict__ x1, int z0,
                                        int wv, int lane, float (&x1c)[4][2][5]) {
    #pragma unroll
    for (int r = 0; r < 4; ++r) {
        const float* b = x1 + (size_t)(z0 + wv*4 + r) * 1152;
        if constexpr (L1 == 0) {
            const float2 t = *reinterpret_cast<const float2*>(b + 2*lane);
            x1c[r][0][0] = t.x; x1c[r][1][0] = t.y;
        } else if constexpr (L1 == 1) {
            float f6[6];
            #pragma unroll
            for (int j = 0; j < 3; ++j) {
                const float2 t = *reinterpret_cast<const float2*>(b + 128 + 6*lane + 2*j);
                f6[2*j] = t.x; f6[2*j + 1] = t.y;
            }
            #pragma unroll
            for (int i = 0; i < 3; ++i) { x1c[r][0][i] = f6[i]; x1c[r][1][i] = f6[3+i]; }
        } else {
            float f10[10];
            #pragma unroll
            for (int j = 0; j < 5; ++j) {
                const float2 t = *reinterpret_cast<const float2*>(b + 512 + 10*lane + 2*j);
                f10[2*j] = t.x; f10[2*j + 1] = t.y;
            }
            #pragma unroll
            for (int i = 0; i < 5; ++i) { x1c[r][0][i] = f10[i]; x1c[r][1][i] = f10[5+i]; }
        }
    }
}

// ---- one step: T -> aQ(ks=0) -> y(next) -> [x1 prefetch] -> barrier ->
//      MFMA ks-outer with aN pair double-buffer (aP live regs 32 -> 16) ----
template<int S>
__device__ __forceinline__ void path_iter(
    int tid, const float* __restrict__ x1, int z0,
    const ushort* __restrict__ Wb, const float* __restrict__ Wsrc, int use_prep,
    float (&x1c)[4][2][5],
    float* __restrict__ yl, ushort* __restrict__ Tl,
    const float* __restrict__ cl, const float* __restrict__ x2l,
    f32x4 (&acc)[5][2])
{
    constexpr int P = cSEQ[S];
    constexpr int l1 = cL1[P], lo = cLO[P];
    constexpr int d1 = 2*l1+1, dO = 2*lo+1;
    constexpr int ipad = (d1 == 5) ? 8 : 4;
    constexpr int span_pad = dO * ipad;
    constexpr int roff = (S & 1) ? 80 : 0;
    const int lane = tid & 63, wv = tid >> 6;
    const int g = lane >> 4, m = lane & 15;

    ushort* Tcur = Tl + roff * 128;                 // ring region (cols x 128 u)
    const float* ycur = yl + (S & 1) * YL_BUF;

    // --- first path: x1 loaded here (later groups prefetched pre-barrier) ---
    if constexpr (S == 0)
        load_x1<l1>(x1, z0, wv, lane, x1c);

    // --- T-phase: thread owns u-pair (2*lane, 2*lane+1), z in {4*wv..4*wv+3}.
    //     y is k-major; stride-128 + XOR swizzle (col&7)<<3, write/read same involution ---
    {
        const int u0 = 2 * lane;
        #pragma unroll
        for (int r = 0; r < 4; ++r) {
            const int z = wv * 4 + r;
            #pragma unroll
            for (int k = 0; k < dO; ++k) {
                const f32x4 y0 = *reinterpret_cast<const f32x4*>(
                    ycur + z * span_pad + k * ipad);
                float s0 = 0.f, s1 = 0.f;
                #pragma unroll
                for (int i = 0; i < ((d1 < 4) ? d1 : 4); ++i) {
                    s0 += x1c[r][0][i] * y0[i];
                    s1 += x1c[r][1][i] * y0[i];
                }
                if constexpr (d1 == 5) {
                    const float y4 = ycur[z * span_pad + k * ipad + 4];
                    s0 += x1c[r][0][4] * y4;
                    s1 += x1c[r][1][4] * y4;
                }
                const int col = z * dO + k;
                union { uint u32; ushort h[2]; } pk;
                pk.h[0] = f2bf(s0);
                pk.h[1] = f2bf(s1);
                const uint idx = (uint)(col * 128 + u0) ^ (uint)((col & 7) << 3);
                *reinterpret_cast<uint*>(Tcur + idx) = pk.u32;
            }
        }
    }

    // --- load ks=0 weight pair only (8 regs; latency hides under y + barrier) ---
    bf16x8 aQ0, aQ1;
    if (use_prep) {
        const ushort* wp = Wb + P * 16384;
        aQ0 = *reinterpret_cast<const bf16x8*>(wp + (wv*32 + m)*128 + g*8);
        aQ1 = *reinterpret_cast<const bf16x8*>(wp + (wv*32 + 16 + m)*128 + g*8);
    } else {
        const float* wp = Wsrc + P * 16384;
        bf16x8 v0, v1;
        #pragma unroll
        for (int e = 0; e < 8; ++e) {
            v0[e] = (short)f2bf(wp[(g*8 + e)*128 + wv*32 + m]);
            v1[e] = (short)f2bf(wp[(g*8 + e)*128 + wv*32 + 16 + m]);
        }
        aQ0 = v0; aQ1 = v1;
    }

    // --- overlap: compute next path's y into the other yl buffer ---
    if constexpr (S < 14)
        compute_y<cSEQ[S + 1]>(tid, cl, x2l, yl + ((S + 1) & 1) * YL_BUF);

    // --- prefetch next l1-group's x1 BEFORE the barrier (T-phase done with x1c;
    //     latency hides under the barrier drain instead of stalling next T) ---
    if constexpr (S < 14) {
        constexpr int nl1 = cL1[cSEQ[S + 1]];
        if constexpr (nl1 != l1)
            load_x1<nl1>(x1, z0, wv, lane, x1c);
    }

    __syncthreads();   // T ready; ring adjacency guarantees no WAR with prev path

    // --- MFMA ks-outer: A-frag read once per (t,ks); weight pair double-buffered ---
    #pragma unroll
    for (int ks = 0; ks < 4; ++ks) {
        bf16x8 aN0, aN1;
        if (ks < 3) {
            if (use_prep) {
                const ushort* wp = Wb + P * 16384;
                aN0 = *reinterpret_cast<const bf16x8*>(wp + (wv*32 + m)*128 + (ks+1)*32 + g*8);
                aN1 = *reinterpret_cast<const bf16x8*>(wp + (wv*32 + 16 + m)*128 + (ks+1)*32 + g*8);
            } else {
                const float* wp = Wsrc + P * 16384;
                bf16x8 v0, v1;
                #pragma unroll
                for (int e = 0; e < 8; ++e) {
                    v0[e] = (short)f2bf(wp[((ks+1)*32 + g*8 + e)*128 + wv*32 + m]);
                    v1[e] = (short)f2bf(wp[((ks+1)*32 + g*8 + e)*128 + wv*32 + 16 + m]);
                }
                aN0 = v0; aN1 = v1;
            }
        }
        #pragma unroll
        for (int t = 0; t < dO; ++t) {
            const uint idx = (uint)((t*16 + m) * 128 + ks*32 + g*8)
                           ^ (uint)(((t*16 + m) & 7) << 3);
            const bf16x8 a = *reinterpret_cast<const bf16x8*>(Tcur + idx);
            acc[t][0] = __builtin_amdgcn_mfma_f32_16x16x32_bf16(a, aQ0, acc[t][0], 0,0,0);
            acc[t][1] = __builtin_amdgcn_mfma_f32_16x16x32_bf16(a, aQ1, acc[t][1], 0,0,0);
        }
        if (ks < 3) { aQ0 = aN0; aQ1 = aN1; }
    }
}

// ---- per-lo epilogue: stage full lo-block (16 z) in ring, then coalesced f4 store ----
template<int LO, bool LAST>
__device__ __forceinline__ void store_pass(const f32x4 (&acc)[5][2], float* __restrict__ out,
                                           float* __restrict__ stage, int z0, int tid)
{
    constexpr int dO = 2*LO + 1;
    constexpr float scale = (LO == 0) ? 0.05103103630798288f    // 1/sqrt(384)
                                      : 0.03608439182435161f;   // 1/sqrt(768)
    const int lane = tid & 63, wv = tid >> 6;
    const int g = lane >> 4, m = lane & 15;
    __syncthreads();                        // ring free (all MFMA reads done)
    #pragma unroll
    for (int t = 0; t < dO; ++t)
    #pragma unroll
    for (int r = 0; r < 4; ++r) {
        const int zcol = t*16 + g*4 + r;
        const int z = zcol / dO, k = zcol - z*dO;
        #pragma unroll
        for (int nt = 0; nt < 2; ++nt) {
            const int w = wv*32 + nt*16 + m;
            stage[z*(128*dO) + w*dO + k] = acc[t][nt][r] * scale;  // stride dO over m: conflict-free
        }
    }
    __syncthreads();                        // staged
    const float4* src = (const float4*)stage;
    #pragma unroll
    for (int it = 0; it < 2*dO; ++it) {
        const int idx = it * 256 + tid;     // [0, 512*dO)
        const int z = idx / (32*dO), rem = idx - z*(32*dO);
        ((float4*)(out + (size_t)(z0 + z)*1152 + cO1[LO]))[rem] = src[idx];
    }
    if constexpr (!LAST) __syncthreads();   // store-reads done before ring reuse
}

__device__ __forceinline__ void zero_acc(f32x4 (&acc)[5][2]) {
    #pragma unroll
    for (int t = 0; t < 5; ++t)
        #pragma unroll
        for (int nt = 0; nt < 2; ++nt)
            acc[t][nt] = (f32x4){0.f, 0.f, 0.f, 0.f};
}

__global__ __launch_bounds__(256, 3)
void tp_main(const float* __restrict__ x1, const float* __restrict__ x2,
             const float* __restrict__ wsrc, const ushort* __restrict__ wb,
             int use_prep, CP cp, float* __restrict__ out)
{
    __shared__ __align__(16) ushort Tl[TL_RING];      // 40.96 KB ring / epilogue stage
    __shared__ __align__(16) float yl[2 * YL_BUF];    // 5.1 KB double-buffered y (k-major)
    __shared__ float cl[615];
    __shared__ float x2l[ZT * 9];

    const int tid = threadIdx.x;
    const int z0 = blockIdx.x * ZT;

    // preload all CG tensors and the x2 tile
    #pragma unroll
    for (int p = 0; p < 15; ++p)
        for (int i = tid; i < cCSZ[p]; i += 256) cl[cCOFF[p] + i] = cp.p[p][i];
    for (int i = tid; i < ZT * 9; i += 256) x2l[i] = x2[(size_t)z0 * 9 + i];

    float x1c[4][2][5];   // current l1-group x1 block (<=40 regs)
    f32x4 acc[5][2];      // current lo-pass accumulator (<=40 regs, AGPR)
    zero_acc(acc);

    __syncthreads();                           // cl / x2l ready
    compute_y<cSEQ[0]>(tid, cl, x2l, yl);      // prime y for first path into yl[0]
    __syncthreads();                           // y ready

    float* stage = (float*)Tl;

    // ---- lo = 0 pass (3 paths) ----
    path_iter< 0>(tid, x1, z0, wb, wsrc, use_prep, x1c, yl, Tl, cl, x2l, acc);
    path_iter< 1>(tid, x1, z0, wb, wsrc, use_prep, x1c, yl, Tl, cl, x2l, acc);
    path_iter< 2>(tid, x1, z0, wb, wsrc, use_prep, x1c, yl, Tl, cl, x2l, acc);
    store_pass<0, false>(acc, out, stage, z0, tid);
    zero_acc(acc);

    // ---- lo = 1 pass (6 paths) ----
    path_iter< 3>(tid, x1, z0, wb, wsrc, use_prep, x1c, yl, Tl, cl, x2l, acc);
    path_iter< 4>(tid, x1, z0, wb, wsrc, use_prep, x1c, yl, Tl, cl, x2l, acc);
    path_iter< 5>(tid, x1, z0, wb, wsrc, use_prep, x1c, yl, Tl, cl, x2l, acc);
    path_iter< 6>(tid, x1, z0, wb, wsrc, use_prep, x1c, yl, Tl, cl, x2l, acc);
    path_iter< 7>(tid, x1, z0, wb, wsrc, use_prep, x1c, yl, Tl, cl, x2l, acc);
    path_iter< 8>(tid, x1, z0, wb, wsrc, use_prep, x1c, yl, Tl, cl, x2l, acc);
    store_pass<1, false>(acc, out, stage, z0, tid);
    zero_acc(acc);

    // ---- lo = 2 pass (6 paths) ----
    path_iter< 9>(tid, x1, z0, wb, wsrc, use_prep, x1c, yl, Tl, cl, x2l, acc);
    path_iter<10>(tid, x1, z0, wb, wsrc, use_prep, x1c, yl, Tl, cl, x2l, acc);
    path_iter<11>(tid, x1, z0, wb, wsrc, use_prep, x1c, yl, Tl, cl, x2l, acc);
    path_iter<12>(tid, x1, z0, wb, wsrc, use_prep, x1c, yl, Tl, cl, x2l, acc);
    path_iter<13>(tid, x1, z0, wb, wsrc, use_prep, x1c, yl, Tl, cl, x2l, acc);
    path_iter<14>(tid, x1, z0, wb, wsrc, use_prep, x1c, yl, Tl, cl, x2l, acc);
    store_pass<2, true>(acc, out, stage, z0, tid);
}

extern "C" void kernel_launch(void* const* d_in, const int* in_sizes, int n_in,
                              void* d_out, int out_size, void* d_ws, size_t ws_size,
                              hipStream_t stream) {
    const float* x1 = (const float*)d_in[0];
    const float* x2 = (const float*)d_in[1];
    const float* ws = (const float*)d_in[2];
    CP cp;
    for (int p = 0; p < 15; ++p) cp.p[p] = (const float*)d_in[3 + p];
    float* out = (float*)d_out;

    const int N = in_sizes[0] / 1152;         // 16384
    const int use_prep = (ws_size >= (size_t)(15 * 128 * 128 * 2)) ? 1 : 0;

    if (use_prep)
        prep_w<<<15, 256, 0, stream>>>(ws, (ushort*)d_ws);
    tp_main<<<N / ZT, 256, 0, stream>>>(x1, x2, ws, (const ushort*)d_ws,
                                        use_prep, cp, out);
}